// Round 1
// baseline (2038.578 us; speedup 1.0000x reference)
//
#include <hip/hip_runtime.h>

#define N_NODES 50000
#define N_EDGES 3200000
#define N_GRAPHS 50
#define IN_F 5
#define HID 64
#define OUT_F 2

// ---------------- degree / norm ----------------
__global__ void k_init_deg(float* deg) {
    int i = blockIdx.x * blockDim.x + threadIdx.x;
    if (i < N_NODES) deg[i] = 1.0f;  // self-loop weight folded in
}

__global__ void k_deg(const int* dst, const float* ew, float* deg) {
    int e = blockIdx.x * blockDim.x + threadIdx.x;
    if (e < N_EDGES) atomicAdd(&deg[dst[e]], ew[e]);
}

// dinv = rsqrt(deg);  p[i] = x[i] * dinv[i]^2   (self-loop term of A_norm @ x)
__global__ void k_dinv_pinit(const float* deg, const float* x, float* dinv, float* p) {
    int i = blockIdx.x * blockDim.x + threadIdx.x;
    if (i < N_NODES) {
        float di = rsqrtf(deg[i]);
        dinv[i] = di;
        float s = di * di;
#pragma unroll
        for (int f = 0; f < IN_F; ++f) p[i * IN_F + f] = x[i * IN_F + f] * s;
    }
}

// ---------------- layer 1: propagate raw x (5 feats), then transform ----------------
__global__ void k_scat1(const int* src, const int* dst, const float* ew,
                        const float* dinv, const float* x, float* p) {
    int e = blockIdx.x * blockDim.x + threadIdx.x;
    if (e < N_EDGES) {
        int s = src[e], d = dst[e];
        float n = dinv[s] * ew[e] * dinv[d];
#pragma unroll
        for (int f = 0; f < IN_F; ++f)
            atomicAdd(&p[d * IN_F + f], x[s * IN_F + f] * n);
    }
}

// h1 = relu(p @ W1 + b1)
__global__ void k_h1(const float* p, const float* W1, const float* b1, float* h1) {
    int t = blockIdx.x * blockDim.x + threadIdx.x;
    int i = t >> 6, j = t & 63;
    if (i < N_NODES) {
        float acc = b1[j];
#pragma unroll
        for (int f = 0; f < IN_F; ++f) acc += p[i * IN_F + f] * W1[f * HID + j];
        h1[i * HID + j] = fmaxf(acc, 0.0f);
    }
}

// ---------------- layer 2: transform first (g = h1 @ W2), then propagate ----------------
__global__ void k_g(const float* h1, const float* W2, float* g) {
    __shared__ float w[HID * HID];
    int t = threadIdx.x;  // 256 threads
    for (int k = t; k < HID * HID; k += 256) w[k] = W2[k];
    __syncthreads();
    int j = t & 63;
    int i0 = blockIdx.x * 16 + (t >> 6);  // nodes i0, i0+4, i0+8, i0+12 (50000 % 16 == 0)
    float acc[4] = {0.f, 0.f, 0.f, 0.f};
    for (int f = 0; f < HID; ++f) {
        float wv = w[f * HID + j];
#pragma unroll
        for (int k = 0; k < 4; ++k)
            acc[k] += h1[(i0 + 4 * k) * HID + f] * wv;
    }
#pragma unroll
    for (int k = 0; k < 4; ++k)
        g[(i0 + 4 * k) * HID + j] = acc[k];
}

// h2 init with self-loop contribution
__global__ void k_h2init(const float* g, const float* dinv, float* h2) {
    int t = blockIdx.x * blockDim.x + threadIdx.x;
    int i = t >> 6;
    if (i < N_NODES) {
        float di = dinv[i];
        h2[t] = g[t] * di * di;
    }
}

// wave-per-edge scatter: lane j handles feature j
__global__ void k_scat2(const int* src, const int* dst, const float* ew,
                        const float* dinv, const float* g, float* h2) {
    int e = blockIdx.x * 4 + (threadIdx.x >> 6);
    int j = threadIdx.x & 63;
    if (e < N_EDGES) {
        int s = src[e], d = dst[e];
        float n = dinv[s] * ew[e] * dinv[d];
        atomicAdd(&h2[d * HID + j], g[s * HID + j] * n);
    }
}

// ---------------- pooling ----------------
__global__ void k_cnt(const int* batch, float* cnt) {
    int i = blockIdx.x * blockDim.x + threadIdx.x;
    if (i < N_NODES) atomicAdd(&cnt[batch[i]], 1.0f);
}

// relu(h2 + b2) fused with per-graph sum; batch is sorted -> running sum + boundary flush
__global__ void k_pool(const float* h2, const float* b2, const int* batch, float* pool) {
    int wave = threadIdx.x >> 6;
    int j = threadIdx.x & 63;
    int base = (blockIdx.x * 4 + wave) * 64;
    float bj = b2[j];
    float acc = 0.f;
    int cur = -1;
    for (int n = 0; n < 64; ++n) {
        int i = base + n;
        if (i >= N_NODES) break;
        int b = batch[i];
        if (b != cur) {
            if (cur >= 0) atomicAdd(&pool[cur * HID + j], acc);
            cur = b;
            acc = 0.f;
        }
        acc += fmaxf(h2[i * HID + j] + bj, 0.0f);
    }
    if (cur >= 0) atomicAdd(&pool[cur * HID + j], acc);
}

__global__ void k_out(const float* pool, const float* cnt, const float* Wo,
                      const float* bo, float* out) {
    int t = blockIdx.x * blockDim.x + threadIdx.x;
    if (t < N_GRAPHS * OUT_F) {
        int gi = t / OUT_F, k = t % OUT_F;
        float c = fmaxf(cnt[gi], 1.0f);
        float acc = bo[k];
        for (int f = 0; f < HID; ++f)
            acc += (pool[gi * HID + f] / c) * Wo[f * OUT_F + k];
        out[t] = acc;
    }
}

extern "C" void kernel_launch(void* const* d_in, const int* in_sizes, int n_in,
                              void* d_out, int out_size, void* d_ws, size_t ws_size,
                              hipStream_t stream) {
    const float* x   = (const float*)d_in[0];
    const int*   ei  = (const int*)d_in[1];
    const float* ea  = (const float*)d_in[2];
    const int*   bat = (const int*)d_in[3];
    const float* W1  = (const float*)d_in[4];
    const float* b1  = (const float*)d_in[5];
    const float* W2  = (const float*)d_in[6];
    const float* b2  = (const float*)d_in[7];
    const float* Wo  = (const float*)d_in[8];
    const float* bo  = (const float*)d_in[9];
    float* out = (float*)d_out;

    const int* src = ei;
    const int* dst = ei + N_EDGES;

    float* ws = (float*)d_ws;
    float* deg  = ws;                    // 50000
    float* dinv = ws + 50000;            // 50000
    float* p    = ws + 100000;           // 250000
    float* h1   = ws + 350000;           // 3,200,000
    float* g    = ws + 3550000;          // 3,200,000
    float* h2   = ws + 6750000;          // 3,200,000
    float* pool = ws + 9950000;          // 3200
    float* cnt  = ws + 9953200;          // 50

    hipMemsetAsync(pool, 0, (3200 + 50) * sizeof(float), stream);

    int nb_nodes = (N_NODES + 255) / 256;
    int nb_edges = (N_EDGES + 255) / 256;

    k_init_deg<<<nb_nodes, 256, 0, stream>>>(deg);
    k_deg<<<nb_edges, 256, 0, stream>>>(dst, ea, deg);
    k_dinv_pinit<<<nb_nodes, 256, 0, stream>>>(deg, x, dinv, p);
    k_scat1<<<nb_edges, 256, 0, stream>>>(src, dst, ea, dinv, x, p);
    k_h1<<<(N_NODES * HID) / 256, 256, 0, stream>>>(p, W1, b1, h1);
    k_g<<<N_NODES / 16, 256, 0, stream>>>(h1, W2, g);
    k_h2init<<<(N_NODES * HID) / 256, 256, 0, stream>>>(g, dinv, h2);
    k_scat2<<<(N_EDGES + 3) / 4, 256, 0, stream>>>(src, dst, ea, dinv, g, h2);
    k_cnt<<<nb_nodes, 256, 0, stream>>>(bat, cnt);
    k_pool<<<(782 + 3) / 4, 256, 0, stream>>>(h2, b2, bat, pool);
    k_out<<<1, 128, 0, stream>>>(pool, cnt, Wo, bo, out);
}

// Round 2
// 1085.312 us; speedup vs baseline: 1.8783x; 1.8783x over previous
//
#include <hip/hip_runtime.h>

#define N_NODES 50000
#define N_EDGES 3200000
#define N_GRAPHS 50
#define IN_F 5
#define HID 64
#define OUT_F 2

// ---------- CSR build: histogram, scan, fill ----------
__global__ void k_hist(const int* dst, int* hist) {
    int e = blockIdx.x * 256 + threadIdx.x;
    if (e < N_EDGES) atomicAdd(&hist[dst[e]], 1);
}

__global__ void k_scan1(const int* hist, int* rp, int* bsum) {
    __shared__ int s[256];
    int t = threadIdx.x;
    int i = blockIdx.x * 256 + t;
    int v = (i < N_NODES) ? hist[i] : 0;
    s[t] = v;
    __syncthreads();
    for (int off = 1; off < 256; off <<= 1) {
        int a = (t >= off) ? s[t - off] : 0;
        __syncthreads();
        s[t] += a;
        __syncthreads();
    }
    if (i < N_NODES) rp[i] = s[t] - v;          // exclusive within chunk
    if (t == 255) bsum[blockIdx.x] = s[255];    // chunk total
}

__global__ void k_scan2(int* bsum, int nblk) {
    __shared__ int s[256];
    int t = threadIdx.x;
    int v = (t < nblk) ? bsum[t] : 0;
    s[t] = v;
    __syncthreads();
    for (int off = 1; off < 256; off <<= 1) {
        int a = (t >= off) ? s[t - off] : 0;
        __syncthreads();
        s[t] += a;
        __syncthreads();
    }
    if (t < nblk) bsum[t] = s[t];               // inclusive
}

__global__ void k_scan3(int* rp, int* cursor, const int* bsum) {
    int i = blockIdx.x * 256 + threadIdx.x;
    if (i < N_NODES) {
        int off = blockIdx.x ? bsum[blockIdx.x - 1] : 0;
        int r = rp[i] + off;
        rp[i] = r;
        cursor[i] = r;
    }
    if (i == 0) rp[N_NODES] = N_EDGES;
}

__global__ void k_fill(const int* src, const int* dst, const float* ew,
                       int* cursor, int* csr_src, float* csr_w) {
    int e = blockIdx.x * 256 + threadIdx.x;
    if (e < N_EDGES) {
        int d = dst[e];
        int slot = atomicAdd(&cursor[d], 1);
        csr_src[slot] = src[e];
        csr_w[slot] = ew[e];
    }
}

// weighted degree (self-loop +1) -> dinv, contiguous row sum, no atomics
__global__ void k_degw(const int* rp, const float* csr_w, float* dinv) {
    int i = blockIdx.x * 256 + threadIdx.x;
    if (i < N_NODES) {
        int b = rp[i], en = rp[i + 1];
        float sum = 1.0f;
        for (int k = b; k < en; ++k) sum += csr_w[k];
        dinv[i] = rsqrtf(sum);
    }
}

// ---------- layer 1 gather: p = A_norm @ x (5 feats); normalizes csr_w in place ----------
__global__ void k_p(const int* rp, const int* csr_src, float* csr_w,
                    const float* dinv, const float* x, float* p) {
    int node = blockIdx.x * 4 + (threadIdx.x >> 6);
    int lane = threadIdx.x & 63;
    if (node >= N_NODES) return;
    int b = rp[node], en = rp[node + 1];
    float di = dinv[node];
    float a0 = 0.f, a1 = 0.f, a2 = 0.f, a3 = 0.f, a4 = 0.f;
    for (int k = b + lane; k < en; k += 64) {
        int s = csr_src[k];
        float n = dinv[s] * csr_w[k] * di;
        csr_w[k] = n;                           // store normalized weight for layer 2
        const float* xs = &x[s * IN_F];
        a0 += xs[0] * n; a1 += xs[1] * n; a2 += xs[2] * n; a3 += xs[3] * n; a4 += xs[4] * n;
    }
    for (int off = 32; off; off >>= 1) {
        a0 += __shfl_down(a0, off); a1 += __shfl_down(a1, off); a2 += __shfl_down(a2, off);
        a3 += __shfl_down(a3, off); a4 += __shfl_down(a4, off);
    }
    if (lane == 0) {
        float s2 = di * di;
        const float* xi = &x[node * IN_F];
        float* pp = &p[node * IN_F];
        pp[0] = a0 + xi[0] * s2; pp[1] = a1 + xi[1] * s2; pp[2] = a2 + xi[2] * s2;
        pp[3] = a3 + xi[3] * s2; pp[4] = a4 + xi[4] * s2;
    }
}

// ---------- fused h1 = relu(p@W1+b1); g = h1@W2 (h1 never materialized) ----------
__global__ void k_h1g(const float* p, const float* W1, const float* b1,
                      const float* W2, float* g) {
    __shared__ float W1s[IN_F * HID];
    __shared__ float W2s[HID * HID];
    __shared__ float b1s[HID];
    int t = threadIdx.x;
    for (int k = t; k < IN_F * HID; k += 256) W1s[k] = W1[k];
    for (int k = t; k < HID * HID; k += 256) W2s[k] = W2[k];
    if (t < HID) b1s[t] = b1[t];
    __syncthreads();
    int lane = t & 63;
    int wid = blockIdx.x * 4 + (t >> 6);
    int nw = gridDim.x * 4;
    for (int node = wid; node < N_NODES; node += nw) {
        const float* pp = &p[node * IN_F];
        float pv0 = pp[0], pv1 = pp[1], pv2 = pp[2], pv3 = pp[3], pv4 = pp[4];
        float h = b1s[lane] + pv0 * W1s[lane] + pv1 * W1s[64 + lane] + pv2 * W1s[128 + lane]
                + pv3 * W1s[192 + lane] + pv4 * W1s[256 + lane];
        h = fmaxf(h, 0.f);
        float acc = 0.f;
#pragma unroll
        for (int f = 0; f < HID; ++f)
            acc += __shfl(h, f) * W2s[f * HID + lane];
        g[node * HID + lane] = acc;
    }
}

// ---------- layer 2 gather fused with bias/relu/pool ----------
__global__ void k_h2g(const int* rp, const int* csr_src, const float* csr_w,
                      const float* dinv, const float* g, const float* b2,
                      const int* batch, float* pool) {
    int t = threadIdx.x, lane = t & 63;
    int wid = blockIdx.x * 4 + (t >> 6), nw = gridDim.x * 4;
    float bj = b2[lane];
    for (int node = wid; node < N_NODES; node += nw) {
        int b = rp[node], en = rp[node + 1];
        float di = dinv[node];
        float acc = g[node * HID + lane] * di * di;   // self-loop
        int k0 = b;
        for (; k0 + 64 <= en; k0 += 64) {
            int sv = csr_src[k0 + lane];
            float wv = csr_w[k0 + lane];
#pragma unroll 8
            for (int tt = 0; tt < 64; ++tt) {
                int s = __shfl(sv, tt);
                float w = __shfl(wv, tt);
                acc += g[s * HID + lane] * w;
            }
        }
        if (k0 < en) {
            int kk = k0 + lane;
            int sv = (kk < en) ? csr_src[kk] : 0;
            float wv = (kk < en) ? csr_w[kk] : 0.f;
            int m = en - k0;
            for (int tt = 0; tt < m; ++tt) {
                int s = __shfl(sv, tt);
                float w = __shfl(wv, tt);
                acc += g[s * HID + lane] * w;
            }
        }
        float h2 = fmaxf(acc + bj, 0.f);
        atomicAdd(&pool[batch[node] * HID + lane], h2);
    }
}

__global__ void k_cnt(const int* batch, float* cnt) {
    int i = blockIdx.x * 256 + threadIdx.x;
    if (i < N_NODES) atomicAdd(&cnt[batch[i]], 1.0f);
}

__global__ void k_out(const float* pool, const float* cnt, const float* Wo,
                      const float* bo, float* out) {
    int t = blockIdx.x * blockDim.x + threadIdx.x;
    if (t < N_GRAPHS * OUT_F) {
        int gi = t / OUT_F, k = t % OUT_F;
        float c = fmaxf(cnt[gi], 1.0f);
        float acc = bo[k];
        for (int f = 0; f < HID; ++f)
            acc += (pool[gi * HID + f] / c) * Wo[f * OUT_F + k];
        out[t] = acc;
    }
}

extern "C" void kernel_launch(void* const* d_in, const int* in_sizes, int n_in,
                              void* d_out, int out_size, void* d_ws, size_t ws_size,
                              hipStream_t stream) {
    const float* x   = (const float*)d_in[0];
    const int*   ei  = (const int*)d_in[1];
    const float* ea  = (const float*)d_in[2];
    const int*   bat = (const int*)d_in[3];
    const float* W1  = (const float*)d_in[4];
    const float* b1  = (const float*)d_in[5];
    const float* W2  = (const float*)d_in[6];
    const float* b2  = (const float*)d_in[7];
    const float* Wo  = (const float*)d_in[8];
    const float* bo  = (const float*)d_in[9];
    float* out = (float*)d_out;

    const int* src = ei;
    const int* dst = ei + N_EDGES;

    // workspace layout (4-byte units)
    float* ws = (float*)d_ws;
    int*   rp      = (int*)(ws);                 // 50001 (rounded 50016)
    int*   cursor  = (int*)(ws + 50016);         // 50000
    float* dinv    = ws + 100016;                // 50000
    int*   bsum    = (int*)(ws + 150016);        // 256
    float* pool    = ws + 150272;                // 3200
    float* cnt     = ws + 153472;                // 50 (+pad to 153536)
    float* p       = ws + 153536;                // 250000 (hist reuses this space)
    int*   hist    = (int*)(ws + 153536);        // 50000 (dead after k_scan1)
    int*   csr_src = (int*)(ws + 403536);        // 3,200,000
    float* csr_w   = ws + 3603536;               // 3,200,000
    float* g       = ws + 6803536;               // 3,200,000
    // total: 10,003,536 floats = 40.0 MB

    const int NB_N = (N_NODES + 255) / 256;      // 196
    const int NB_E = (N_EDGES + 255) / 256;      // 12500

    hipMemsetAsync(hist, 0, N_NODES * sizeof(int), stream);
    hipMemsetAsync(pool, 0, (N_GRAPHS * HID + 64) * sizeof(float), stream);

    k_hist <<<NB_E, 256, 0, stream>>>(dst, hist);
    k_scan1<<<NB_N, 256, 0, stream>>>(hist, rp, bsum);
    k_scan2<<<1,    256, 0, stream>>>(bsum, NB_N);
    k_scan3<<<NB_N, 256, 0, stream>>>(rp, cursor, bsum);
    k_fill <<<NB_E, 256, 0, stream>>>(src, dst, ea, cursor, csr_src, csr_w);
    k_degw <<<NB_N, 256, 0, stream>>>(rp, csr_w, dinv);
    k_p    <<<(N_NODES + 3) / 4, 256, 0, stream>>>(rp, csr_src, csr_w, dinv, x, p);
    k_h1g  <<<1024, 256, 0, stream>>>(p, W1, b1, W2, g);
    k_cnt  <<<NB_N, 256, 0, stream>>>(bat, cnt);
    k_h2g  <<<2048, 256, 0, stream>>>(rp, csr_src, csr_w, dinv, g, b2, bat, pool);
    k_out  <<<1, 128, 0, stream>>>(pool, cnt, Wo, bo, out);
}

// Round 3
// 772.226 us; speedup vs baseline: 2.6399x; 1.4054x over previous
//
#include <hip/hip_runtime.h>

#define N_NODES 50000
#define N_EDGES 3200000
#define N_GRAPHS 50
#define IN_F 5
#define HID 64
#define OUT_F 2

// ---------- CSR build: histogram, scan, fill ----------
__global__ void k_hist(const int* dst, int* hist) {
    int e = blockIdx.x * 256 + threadIdx.x;
    if (e < N_EDGES) atomicAdd(&hist[dst[e]], 1);
}

__global__ void k_scan1(const int* hist, int* rp, int* bsum) {
    __shared__ int s[256];
    int t = threadIdx.x;
    int i = blockIdx.x * 256 + t;
    int v = (i < N_NODES) ? hist[i] : 0;
    s[t] = v;
    __syncthreads();
    for (int off = 1; off < 256; off <<= 1) {
        int a = (t >= off) ? s[t - off] : 0;
        __syncthreads();
        s[t] += a;
        __syncthreads();
    }
    if (i < N_NODES) rp[i] = s[t] - v;          // exclusive within chunk
    if (t == 255) bsum[blockIdx.x] = s[255];    // chunk total
}

__global__ void k_scan2(int* bsum, int nblk) {
    __shared__ int s[256];
    int t = threadIdx.x;
    int v = (t < nblk) ? bsum[t] : 0;
    s[t] = v;
    __syncthreads();
    for (int off = 1; off < 256; off <<= 1) {
        int a = (t >= off) ? s[t - off] : 0;
        __syncthreads();
        s[t] += a;
        __syncthreads();
    }
    if (t < nblk) bsum[t] = s[t];               // inclusive
}

__global__ void k_scan3(int* rp, int* cursor, const int* bsum) {
    int i = blockIdx.x * 256 + threadIdx.x;
    if (i < N_NODES) {
        int off = blockIdx.x ? bsum[blockIdx.x - 1] : 0;
        int r = rp[i] + off;
        rp[i] = r;
        cursor[i] = r;
    }
    if (i == 0) rp[N_NODES] = N_EDGES;
}

// pack (src, weight) into a single 8B scattered store
__global__ void k_fill(const int* src, const int* dst, const float* ew,
                       int* cursor, int2* csr) {
    int e = blockIdx.x * 256 + threadIdx.x;
    if (e < N_EDGES) {
        int d = dst[e];
        int slot = atomicAdd(&cursor[d], 1);
        csr[slot] = make_int2(src[e], __float_as_int(ew[e]));
    }
}

// weighted degree (self-loop +1) -> dinv, contiguous row sum, no atomics
__global__ void k_degw(const int* rp, const int2* csr, float* dinv) {
    int i = blockIdx.x * 256 + threadIdx.x;
    if (i < N_NODES) {
        int b = rp[i], en = rp[i + 1];
        float sum = 1.0f;
        for (int k = b; k < en; ++k) sum += __int_as_float(csr[k].y);
        dinv[i] = rsqrtf(sum);
    }
}

// ---------- layer 1 gather: p = di*(sum w*dinv[s]*x[s] + di*x[node]) ----------
__global__ void k_p(const int* rp, const int2* csr, const float* dinv,
                    const float* x, float* p) {
    int node = blockIdx.x * 4 + (threadIdx.x >> 6);
    int lane = threadIdx.x & 63;
    if (node >= N_NODES) return;
    int b = rp[node], en = rp[node + 1];
    float a0 = 0.f, a1 = 0.f, a2 = 0.f, a3 = 0.f, a4 = 0.f;
    for (int k = b + lane; k < en; k += 64) {
        int2 ev = csr[k];
        int s = ev.x;
        float n = dinv[s] * __int_as_float(ev.y);
        const float* xs = &x[s * IN_F];
        a0 += xs[0] * n; a1 += xs[1] * n; a2 += xs[2] * n; a3 += xs[3] * n; a4 += xs[4] * n;
    }
    for (int off = 32; off; off >>= 1) {
        a0 += __shfl_down(a0, off); a1 += __shfl_down(a1, off); a2 += __shfl_down(a2, off);
        a3 += __shfl_down(a3, off); a4 += __shfl_down(a4, off);
    }
    if (lane == 0) {
        float di = dinv[node];
        const float* xi = &x[node * IN_F];
        float* pp = &p[node * IN_F];
        pp[0] = di * (a0 + di * xi[0]); pp[1] = di * (a1 + di * xi[1]);
        pp[2] = di * (a2 + di * xi[2]); pp[3] = di * (a3 + di * xi[3]);
        pp[4] = di * (a4 + di * xi[4]);
    }
}

// ---------- fused h1 = relu(p@W1+b1); g' = (h1@W2)*dinv (h1 never materialized) ----------
__global__ void k_h1g(const float* p, const float* W1, const float* b1,
                      const float* W2, const float* dinv, float* g) {
    __shared__ float W1s[IN_F * HID];
    __shared__ float W2s[HID * HID];
    __shared__ float b1s[HID];
    int t = threadIdx.x;
    for (int k = t; k < IN_F * HID; k += 256) W1s[k] = W1[k];
    for (int k = t; k < HID * HID; k += 256) W2s[k] = W2[k];
    if (t < HID) b1s[t] = b1[t];
    __syncthreads();
    int lane = t & 63;
    int wid = blockIdx.x * 4 + (t >> 6);
    int nw = gridDim.x * 4;
    for (int node = wid; node < N_NODES; node += nw) {
        const float* pp = &p[node * IN_F];
        float pv0 = pp[0], pv1 = pp[1], pv2 = pp[2], pv3 = pp[3], pv4 = pp[4];
        float h = b1s[lane] + pv0 * W1s[lane] + pv1 * W1s[64 + lane] + pv2 * W1s[128 + lane]
                + pv3 * W1s[192 + lane] + pv4 * W1s[256 + lane];
        h = fmaxf(h, 0.f);
        float acc = 0.f;
#pragma unroll
        for (int f = 0; f < HID; ++f)
            acc += __shfl(h, f) * W2s[f * HID + lane];
        g[node * HID + lane] = acc * dinv[node];   // pre-scaled by dinv
    }
}

// ---------- layer 2 gather fused with bias/relu/pool (contiguous chunks/wave) ----------
#define CHUNK 7
__global__ void k_h2g(const int* rp, const int2* csr, const float* dinv,
                      const float* g, const float* b2, const int* batch, float* pool) {
    int t = threadIdx.x, lane = t & 63;
    int wid = blockIdx.x * 4 + (t >> 6);
    int n0 = wid * CHUNK;
    if (n0 >= N_NODES) return;
    int n1 = min(n0 + CHUNK, N_NODES);
    float bj = b2[lane];
    float accp = 0.f;
    int cur = batch[n0];
    for (int node = n0; node < n1; ++node) {
        int b = rp[node], en = rp[node + 1];
        float acc = g[node * HID + lane];          // self-loop (g' = g*dinv)
        int k0 = b;
        for (; k0 + 64 <= en; k0 += 64) {
            int2 ev = csr[k0 + lane];
            int sv = ev.x;
            float wv = __int_as_float(ev.y);
#pragma unroll 8
            for (int tt = 0; tt < 64; ++tt) {
                int s = __shfl(sv, tt);
                float w = __shfl(wv, tt);
                acc += g[s * HID + lane] * w;
            }
        }
        if (k0 < en) {
            int kk = k0 + lane;
            int2 ev = (kk < en) ? csr[kk] : make_int2(0, 0);
            int sv = ev.x;
            float wv = __int_as_float(ev.y);
            int m = en - k0;
            for (int tt = 0; tt < m; ++tt) {
                int s = __shfl(sv, tt);
                float w = __shfl(wv, tt);
                acc += g[s * HID + lane] * w;
            }
        }
        float h2 = fmaxf(dinv[node] * acc + bj, 0.f);
        int bb = batch[node];
        if (bb != cur) {
            atomicAdd(&pool[cur * HID + lane], accp);
            cur = bb;
            accp = 0.f;
        }
        accp += h2;
    }
    atomicAdd(&pool[cur * HID + lane], accp);
}

__device__ int lowb(const int* a, int n, int v) {
    int lo = 0, hi = n;
    while (lo < hi) { int m = (lo + hi) >> 1; if (a[m] < v) lo = m + 1; else hi = m; }
    return lo;
}

__global__ void k_out(const float* pool, const int* batch, const float* Wo,
                      const float* bo, float* out) {
    int t = blockIdx.x * blockDim.x + threadIdx.x;
    if (t < N_GRAPHS * OUT_F) {
        int gi = t / OUT_F, k = t % OUT_F;
        int c = lowb(batch, N_NODES, gi + 1) - lowb(batch, N_NODES, gi);
        float cf = fmaxf((float)c, 1.0f);
        float acc = bo[k];
        for (int f = 0; f < HID; ++f)
            acc += (pool[gi * HID + f] / cf) * Wo[f * OUT_F + k];
        out[t] = acc;
    }
}

extern "C" void kernel_launch(void* const* d_in, const int* in_sizes, int n_in,
                              void* d_out, int out_size, void* d_ws, size_t ws_size,
                              hipStream_t stream) {
    const float* x   = (const float*)d_in[0];
    const int*   ei  = (const int*)d_in[1];
    const float* ea  = (const float*)d_in[2];
    const int*   bat = (const int*)d_in[3];
    const float* W1  = (const float*)d_in[4];
    const float* b1  = (const float*)d_in[5];
    const float* W2  = (const float*)d_in[6];
    const float* b2  = (const float*)d_in[7];
    const float* Wo  = (const float*)d_in[8];
    const float* bo  = (const float*)d_in[9];
    float* out = (float*)d_out;

    const int* src = ei;
    const int* dst = ei + N_EDGES;

    // workspace layout (4-byte units) — total 10,003,536 floats = 40.0 MB
    float* ws = (float*)d_ws;
    int*   rp      = (int*)(ws);                 // 50001 (pad 50016)
    int*   cursor  = (int*)(ws + 50016);         // 50000
    float* dinv    = ws + 100016;                // 50000
    int*   bsum    = (int*)(ws + 150016);        // 256
    float* pool    = ws + 150272;                // 3200 (+pad to 153536)
    float* p       = ws + 153536;                // 250000 (hist overlaps first 50000)
    int*   hist    = (int*)(ws + 153536);        // 50000, dead after k_scan1
    int2*  csr     = (int2*)(ws + 403536);       // 3,200,000 int2 = 6,400,000 floats
    float* g       = ws + 6803536;               // 3,200,000

    const int NB_N = (N_NODES + 255) / 256;      // 196
    const int NB_E = (N_EDGES + 255) / 256;      // 12500

    hipMemsetAsync(hist, 0, N_NODES * sizeof(int), stream);
    hipMemsetAsync(pool, 0, N_GRAPHS * HID * sizeof(float), stream);

    k_hist <<<NB_E, 256, 0, stream>>>(dst, hist);
    k_scan1<<<NB_N, 256, 0, stream>>>(hist, rp, bsum);
    k_scan2<<<1,    256, 0, stream>>>(bsum, NB_N);
    k_scan3<<<NB_N, 256, 0, stream>>>(rp, cursor, bsum);
    k_fill <<<NB_E, 256, 0, stream>>>(src, dst, ea, cursor, csr);
    k_degw <<<NB_N, 256, 0, stream>>>(rp, csr, dinv);
    k_p    <<<(N_NODES + 3) / 4, 256, 0, stream>>>(rp, csr, dinv, x, p);
    k_h1g  <<<1024, 256, 0, stream>>>(p, W1, b1, W2, dinv, g);
    k_h2g  <<<(50000 / CHUNK / 4) + 1, 256, 0, stream>>>(rp, csr, dinv, g, b2, bat, pool);
    k_out  <<<1, 128, 0, stream>>>(pool, bat, Wo, bo, out);
}